// Round 1
// baseline (365.636 us; speedup 1.0000x reference)
//
#include <hip/hip_runtime.h>
#include <stdint.h>

typedef unsigned short ushort_t;
typedef __attribute__((ext_vector_type(8))) short short8;
typedef __attribute__((ext_vector_type(4))) float float4v;
typedef __attribute__((ext_vector_type(4))) unsigned short ushort4v;

static __device__ __forceinline__ ushort_t f2bf(float f) {
  unsigned u = __builtin_bit_cast(unsigned, f);
  u += 0x7fffu + ((u >> 16) & 1u);   // round-to-nearest-even
  return (ushort_t)(u >> 16);
}
static __device__ __forceinline__ float bf2f(ushort_t h) {
  unsigned u = ((unsigned)h) << 16;
  return __builtin_bit_cast(float, u);
}

// ---------------- elementwise / transform kernels ----------------

// fp32 -> bf16 straight cast, 4 elems/thread. n4 = n/4.
__global__ void cast_f32_bf16(const float* __restrict__ in, ushort_t* __restrict__ out, int n4) {
  int i = blockIdx.x * 256 + threadIdx.x;
  if (i < n4) {
    float4v v = *(const float4v*)(in + (size_t)i * 4);
    ushort4v o;
    o[0] = f2bf(v[0]); o[1] = f2bf(v[1]); o[2] = f2bf(v[2]); o[3] = f2bf(v[3]);
    *(ushort4v*)(out + (size_t)i * 4) = o;
  }
}

// P = bf16(exp(pb)), 1 elem/thread
__global__ void exp_cast(const float* __restrict__ in, ushort_t* __restrict__ out, int n) {
  int i = blockIdx.x * 256 + threadIdx.x;
  if (i < n) out[i] = f2bf(expf(in[i]));
}

// out[c][r] = bf16(in[r][c]); in is R x C fp32 row-major. grid (C/32, R/32), block 256.
__global__ void transpose_cast(const float* __restrict__ in, ushort_t* __restrict__ out,
                               int R, int C) {
  __shared__ float t[32][33];
  int tx = threadIdx.x & 31, ty = threadIdx.x >> 5;  // ty in [0,8)
  int c = blockIdx.x * 32 + tx;
  #pragma unroll
  for (int i = ty; i < 32; i += 8)
    t[i][tx] = in[(size_t)(blockIdx.y * 32 + i) * C + c];
  __syncthreads();
  int r = blockIdx.y * 32 + tx;
  #pragma unroll
  for (int i = ty; i < 32; i += 8)
    out[(size_t)(blockIdx.x * 32 + i) * R + r] = f2bf(t[tx][i]);
}

// Build GT [8192 x 2048] bf16: rows c in [0,4096) = exp(k)*v, rows 4096+c = exp(k),
// where c = b*1024 + d, cols are t. qkv is bf16 [8192 x 3072], row = t*4+b.
// grid (T/64=32, D/64=16, B=4), block 256.
__global__ void build_gt(const ushort_t* __restrict__ qkv, ushort_t* __restrict__ GT) {
  __shared__ ushort_t gs[64][66];
  __shared__ ushort_t es[64][66];
  int t0 = blockIdx.x * 64, d0 = blockIdx.y * 64, b = blockIdx.z;
  int tx = threadIdx.x & 63, ty = threadIdx.x >> 6;  // ty in [0,4)
  #pragma unroll
  for (int i = ty; i < 64; i += 4) {
    size_t base = (size_t)((t0 + i) * 4 + b) * 3072;
    float kk = bf2f(qkv[base + 1024 + d0 + tx]);
    float vv = bf2f(qkv[base + 2048 + d0 + tx]);
    float ek = expf(kk);
    gs[i][tx] = f2bf(ek * vv);
    es[i][tx] = f2bf(ek);
  }
  __syncthreads();
  #pragma unroll
  for (int i = ty; i < 64; i += 4) {
    int c = b * 1024 + d0 + i;
    GT[(size_t)c * 2048 + t0 + tx]          = gs[tx][i];
    GT[(size_t)(4096 + c) * 2048 + t0 + tx] = es[tx][i];
  }
}

// Y[t*4096 + c] = bf16( sigmoid(q[t,c]) * H[t][c] / H[t][4096+c] ), c = b*1024+d
__global__ void make_y(const float* __restrict__ H, const ushort_t* __restrict__ qkv,
                       ushort_t* __restrict__ Y) {
  int idx = blockIdx.x * 256 + threadIdx.x;  // [0, 2048*4096)
  int t = idx >> 12, c = idx & 4095;
  int b = c >> 10, d = c & 1023;
  float q = bf2f(qkv[(size_t)(t * 4 + b) * 3072 + d]);
  float s = 1.0f / (1.0f + expf(-q));
  float num = H[(size_t)t * 8192 + c];
  float den = H[(size_t)t * 8192 + 4096 + c];
  Y[idx] = f2bf(s * num / den);
}

// ---------------- bf16 MFMA GEMM: C[M,N] = A[M,K] @ BT[N,K]^T (+bias) ----------------
// EPI 0: bf16 store with bias; EPI 1: fp32 store no bias; EPI 2: fp32 store with bias.
// grid (N/128, M/128), block 256 (4 waves). M,N % 128 == 0, K % 32 == 0.
template <int EPI>
__global__ __launch_bounds__(256)
void gemm_bt(const ushort_t* __restrict__ A, const ushort_t* __restrict__ BT,
             const float* __restrict__ bias, float* __restrict__ Cf,
             ushort_t* __restrict__ Cb, int M, int N, int K) {
  __shared__ short8 As[512];  // 128 rows x 32 k (bf16) = 8 KB
  __shared__ short8 Bs[512];
  const int tid  = threadIdx.x;
  const int wid  = tid >> 6;
  const int lane = tid & 63;
  const int wr = wid >> 1, wc = wid & 1;
  const int m16 = lane & 15, quad = lane >> 4;
  const int n0 = blockIdx.x * 128, m0 = blockIdx.y * 128;

  float4v acc[4][4];
  #pragma unroll
  for (int i = 0; i < 4; ++i)
    #pragma unroll
    for (int j = 0; j < 4; ++j)
      #pragma unroll
      for (int r = 0; r < 4; ++r) acc[i][j][r] = 0.0f;

  const int c0 = tid, c1 = tid + 256;
  const int row0 = c0 >> 2, ke0 = (c0 & 3) * 8;
  const int row1 = c1 >> 2, ke1 = (c1 & 3) * 8;

  for (int k0 = 0; k0 < K; k0 += 32) {
    short8 ra0 = *(const short8*)(A  + (size_t)(m0 + row0) * K + k0 + ke0);
    short8 ra1 = *(const short8*)(A  + (size_t)(m0 + row1) * K + k0 + ke1);
    short8 rb0 = *(const short8*)(BT + (size_t)(n0 + row0) * K + k0 + ke0);
    short8 rb1 = *(const short8*)(BT + (size_t)(n0 + row1) * K + k0 + ke1);
    __syncthreads();
    As[c0] = ra0; As[c1] = ra1;
    Bs[c0] = rb0; Bs[c1] = rb1;
    __syncthreads();
    short8 af[4], bfr[4];
    #pragma unroll
    for (int i = 0; i < 4; ++i) af[i]  = As[(wr * 64 + i * 16 + m16) * 4 + quad];
    #pragma unroll
    for (int j = 0; j < 4; ++j) bfr[j] = Bs[(wc * 64 + j * 16 + m16) * 4 + quad];
    #pragma unroll
    for (int i = 0; i < 4; ++i)
      #pragma unroll
      for (int j = 0; j < 4; ++j)
        acc[i][j] = __builtin_amdgcn_mfma_f32_16x16x32_bf16(af[i], bfr[j], acc[i][j], 0, 0, 0);
  }

  #pragma unroll
  for (int i = 0; i < 4; ++i)
    #pragma unroll
    for (int j = 0; j < 4; ++j) {
      const int gm = m0 + wr * 64 + i * 16 + quad * 4;
      const int gn = n0 + wc * 64 + j * 16 + m16;
      const float bv = (EPI == 1) ? 0.0f : bias[gn];
      #pragma unroll
      for (int r = 0; r < 4; ++r) {
        float v = acc[i][j][r] + bv;
        if (EPI == 0) Cb[(size_t)(gm + r) * N + gn] = f2bf(v);
        else          Cf[(size_t)(gm + r) * N + gn] = v;
      }
    }
}

// ---------------- launch ----------------

extern "C" void kernel_launch(void* const* d_in, const int* in_sizes, int n_in,
                              void* d_out, int out_size, void* d_ws, size_t ws_size,
                              hipStream_t stream) {
  const float* data = (const float*)d_in[0];  // [2048,4,1024]
  const float* Wqkv = (const float*)d_in[1];  // [1024,3072]
  const float* bqkv = (const float*)d_in[2];  // [3072]
  const float* pb   = (const float*)d_in[3];  // [2048,2048]
  const float* Wout = (const float*)d_in[4];  // [1024,1024]
  const float* bout = (const float*)d_in[5];  // [1024]
  float* out = (float*)d_out;                 // [2048,4,1024] fp32

  char* ws = (char*)d_ws;
  ushort_t* Xb    = (ushort_t*)(ws);                        // 16 MB  [8192,1024] bf16
  ushort_t* WqkvT = (ushort_t*)(ws + (16ull << 20));        // 6 MB   [3072,1024] bf16
  ushort_t* WoutT = (ushort_t*)(ws + (22ull << 20));        // 2 MB   [1024,1024] bf16
  ushort_t* Pb    = (ushort_t*)(ws + (24ull << 20));        // 8 MB   [2048,2048] bf16
  ushort_t* qkvb  = (ushort_t*)(ws + (32ull << 20));        // 48 MB  [8192,3072] bf16
  ushort_t* GT    = (ushort_t*)(ws + (80ull << 20));        // 32 MB  [8192,2048] bf16
  float*    H     = (float*)   (ws + (112ull << 20));       // 64 MB  [2048,8192] fp32
  ushort_t* Y     = (ushort_t*)(ws + (176ull << 20));       // 16 MB  [2048,4096] bf16
  // total 192 MB

  cast_f32_bf16<<<8192, 256, 0, stream>>>(data, Xb, 2097152);
  transpose_cast<<<dim3(96, 32), 256, 0, stream>>>(Wqkv, WqkvT, 1024, 3072);
  transpose_cast<<<dim3(32, 32), 256, 0, stream>>>(Wout, WoutT, 1024, 1024);
  exp_cast<<<16384, 256, 0, stream>>>(pb, Pb, 4194304);

  // qkv = X @ Wqkv + b, stored bf16
  gemm_bt<0><<<dim3(24, 64), 256, 0, stream>>>(Xb, WqkvT, bqkv, nullptr, qkvb, 8192, 3072, 1024);
  // GT rows: [0,4096) = exp(k)*v, [4096,8192) = exp(k)
  build_gt<<<dim3(32, 16, 4), 256, 0, stream>>>(qkvb, GT);
  // H = exp(pb) @ G  -> [num | den]
  gemm_bt<1><<<dim3(64, 16), 256, 0, stream>>>(Pb, GT, nullptr, H, nullptr, 2048, 8192, 2048);
  // Y = sigmoid(q) * num / den
  make_y<<<32768, 256, 0, stream>>>(H, qkvb, Y);
  // out = Y @ Wout + b
  gemm_bt<2><<<dim3(8, 64), 256, 0, stream>>>(Y, WoutT, bout, out, nullptr, 8192, 1024, 1024);
}